// Round 9
// baseline (584.776 us; speedup 1.0000x reference)
//
#include <hip/hip_runtime.h>
#include <math.h>

#define D 128
#define H 8
#define HD 16

typedef __attribute__((ext_vector_type(8))) short bf16x8;
typedef __attribute__((ext_vector_type(4))) float f32x4;

#define GLOBAL_AS __attribute__((address_space(1)))
#define LDS_AS    __attribute__((address_space(3)))

__device__ __forceinline__ ushort f2bf(float x) {
    union { float f; unsigned u; } v; v.f = x;
    unsigned r = v.u + 0x7fffu + ((v.u >> 16) & 1u);   // RNE
    return (ushort)(r >> 16);
}
__device__ __forceinline__ float bflo(unsigned u) {
    union { unsigned u; float f; } x; x.u = u << 16; return x.f;
}
__device__ __forceinline__ float bfhi(unsigned u) {
    union { unsigned u; float f; } x; x.u = u & 0xffff0000u; return x.f;
}
__device__ __forceinline__ float bf2f(short s) {
    union { unsigned u; float f; } x; x.u = ((unsigned)(ushort)s) << 16; return x.f;
}

__device__ __forceinline__ float dot16(const float* qf, uint4 a, uint4 b) {
    float w;
    w  = qf[0]  * bflo(a.x) + qf[1]  * bfhi(a.x);
    w += qf[2]  * bflo(a.y) + qf[3]  * bfhi(a.y);
    w += qf[4]  * bflo(a.z) + qf[5]  * bfhi(a.z);
    w += qf[6]  * bflo(a.w) + qf[7]  * bfhi(a.w);
    w += qf[8]  * bflo(b.x) + qf[9]  * bfhi(b.x);
    w += qf[10] * bflo(b.y) + qf[11] * bfhi(b.y);
    w += qf[12] * bflo(b.z) + qf[13] * bfhi(b.z);
    w += qf[14] * bflo(b.w) + qf[15] * bfhi(b.w);
    return w;
}
__device__ __forceinline__ void acc16(float* num, float e, uint4 a, uint4 b) {
    num[0]  = fmaf(e, bflo(a.x), num[0]);  num[1]  = fmaf(e, bfhi(a.x), num[1]);
    num[2]  = fmaf(e, bflo(a.y), num[2]);  num[3]  = fmaf(e, bfhi(a.y), num[3]);
    num[4]  = fmaf(e, bflo(a.z), num[4]);  num[5]  = fmaf(e, bfhi(a.z), num[5]);
    num[6]  = fmaf(e, bflo(a.w), num[6]);  num[7]  = fmaf(e, bfhi(a.w), num[7]);
    num[8]  = fmaf(e, bflo(b.x), num[8]);  num[9]  = fmaf(e, bfhi(b.x), num[9]);
    num[10] = fmaf(e, bflo(b.y), num[10]); num[11] = fmaf(e, bfhi(b.y), num[11]);
    num[12] = fmaf(e, bflo(b.z), num[12]); num[13] = fmaf(e, bfhi(b.z), num[13]);
    num[14] = fmaf(e, bflo(b.w), num[14]); num[15] = fmaf(e, bfhi(b.w), num[15]);
}

// ---------------------------------------------------------------------------
// GEMM v8: v7's LDS A-staging + SWAPPED MFMA operands (R2-verified layout).
// mfma(A=Wfrag, B=Afrag) -> D[wcol][arow]: lane holds arow = s*16 + lr and
// 4 CONSECUTIVE wcols = colbase + ct*16 + lq*4 + (0..3). Epilogue becomes
// 4x ushort4 stores (8B) instead of 16x scalar 2B, residual loads become
// float4 — 4x fewer VMEM ops drained by each barrier's vmcnt(0).
// EPI: 0 = bias; 2 = bias+leaky; 3 = bias + fp32 residual. STATS: fused
// per-column BN raw sums (reduce over lr lanes, atomics from lr==0).
// ---------------------------------------------------------------------------
template<int EPI, int M, int STATS>
__global__ __launch_bounds__(256)
void gemm_v8_kernel(const ushort* __restrict__ A,
                    const ushort* __restrict__ W,
                    const float* __restrict__ bias,
                    const float* __restrict__ extf,
                    ushort* __restrict__ outb,
                    float* __restrict__ stats,
                    int N)
{
    __shared__ ushort alds[2][32 * 128];   // 2 x 8KB

    const int lane = threadIdx.x & 63, wave = threadIdx.x >> 6;
    const int lr = lane & 15, lq = lane >> 4;
    const int colbase = blockIdx.y * 128 + wave * 32;

    // resident B(W): 2 col-groups x 4 k-tiles; as A-operand its "row" = lr = wcol
    bf16x8 bfr[2][4];
    {
        const ushort* wp = W + (size_t)(colbase + lr) * 128 + lq * 8;
        #pragma unroll
        for (int ct = 0; ct < 2; ++ct)
            #pragma unroll
            for (int t = 0; t < 4; ++t)
                bfr[ct][t] = *(const bf16x8*)(wp + (size_t)ct * 16 * 128 + t * 32);
    }
    float4 biasv[2];
    biasv[0] = *(const float4*)&bias[colbase + lq * 4];
    biasv[1] = *(const float4*)&bias[colbase + 16 + lq * 4];

    float ssum[2][4] = {}, ssq[2][4] = {};

    auto stage = [&](int rb, int b) {
        #pragma unroll
        for (int i = 0; i < 2; ++i) {
            int r = wave * 8 + i * 4 + (lane >> 4);
            int gr = min(rb + r, N - 1);
            int c = (lane & 15) ^ (r & 7);
            __builtin_amdgcn_global_load_lds(
                (const GLOBAL_AS void*)(A + (size_t)gr * 128 + c * 8),
                (LDS_AS void*)(&alds[b][(wave * 8 + i * 4) * 128]),
                16, 0, 0);
        }
    };

    const int stride = gridDim.x * 32;
    int r0 = blockIdx.x * 32;

    stage(r0, 0);
    __syncthreads();
    int cur = 0;

    while (true) {
        int rn = r0 + stride;
        if (rn < N) stage(rn, cur ^ 1);    // async, overlaps compute below

        bf16x8 a[2][4];
        #pragma unroll
        for (int s = 0; s < 2; ++s) {
            const ushort* lp = &alds[cur][(s * 16 + lr) * 128];
            #pragma unroll
            for (int t = 0; t < 4; ++t)
                a[s][t] = *(const bf16x8*)(lp + ((t * 4 + lq) ^ (lr & 7)) * 8);
        }

        // swapped: D[i = wcol = lq*4+r][j = arow = lr]
        f32x4 acc[2][2] = {};   // [s][ct]
        #pragma unroll
        for (int t = 0; t < 4; ++t) {
            acc[0][0] = __builtin_amdgcn_mfma_f32_16x16x32_bf16(bfr[0][t], a[0][t], acc[0][0], 0, 0, 0);
            acc[1][0] = __builtin_amdgcn_mfma_f32_16x16x32_bf16(bfr[0][t], a[1][t], acc[1][0], 0, 0, 0);
            acc[0][1] = __builtin_amdgcn_mfma_f32_16x16x32_bf16(bfr[1][t], a[0][t], acc[0][1], 0, 0, 0);
            acc[1][1] = __builtin_amdgcn_mfma_f32_16x16x32_bf16(bfr[1][t], a[1][t], acc[1][1], 0, 0, 0);
        }

        #pragma unroll
        for (int ct = 0; ct < 2; ++ct) {
            int cb = colbase + ct * 16 + lq * 4;
            #pragma unroll
            for (int s = 0; s < 2; ++s) {
                int grow = r0 + s * 16 + lr;
                if (grow >= N) continue;
                size_t o = (size_t)grow * M + cb;
                float v0 = acc[s][ct][0] + biasv[ct].x;
                float v1 = acc[s][ct][1] + biasv[ct].y;
                float v2 = acc[s][ct][2] + biasv[ct].z;
                float v3 = acc[s][ct][3] + biasv[ct].w;
                if (EPI == 2) {
                    v0 = v0 > 0.f ? v0 : 0.01f * v0;
                    v1 = v1 > 0.f ? v1 : 0.01f * v1;
                    v2 = v2 > 0.f ? v2 : 0.01f * v2;
                    v3 = v3 > 0.f ? v3 : 0.01f * v3;
                } else if (EPI == 3) {
                    float4 e = *(const float4*)(extf + o);
                    v0 += e.x; v1 += e.y; v2 += e.z; v3 += e.w;
                }
                if (STATS) {
                    ssum[ct][0] += v0; ssq[ct][0] = fmaf(v0, v0, ssq[ct][0]);
                    ssum[ct][1] += v1; ssq[ct][1] = fmaf(v1, v1, ssq[ct][1]);
                    ssum[ct][2] += v2; ssq[ct][2] = fmaf(v2, v2, ssq[ct][2]);
                    ssum[ct][3] += v3; ssq[ct][3] = fmaf(v3, v3, ssq[ct][3]);
                }
                ushort4 st;
                st.x = f2bf(v0); st.y = f2bf(v1); st.z = f2bf(v2); st.w = f2bf(v3);
                *(ushort4*)(outb + o) = st;
            }
        }

        if (rn >= N) break;
        __syncthreads();
        cur ^= 1;
        r0 = rn;
    }

    if (STATS) {
        #pragma unroll
        for (int ct = 0; ct < 2; ++ct) {
            #pragma unroll
            for (int i = 0; i < 4; ++i) {
                float a = ssum[ct][i], b = ssq[ct][i];
                a += __shfl_xor(a, 1, 64);  b += __shfl_xor(b, 1, 64);
                a += __shfl_xor(a, 2, 64);  b += __shfl_xor(b, 2, 64);
                a += __shfl_xor(a, 4, 64);  b += __shfl_xor(b, 4, 64);
                a += __shfl_xor(a, 8, 64);  b += __shfl_xor(b, 8, 64);
                if (lr == 0) {
                    int col = colbase + ct * 16 + lq * 4 + i;
                    unsafeAtomicAdd(&stats[col], a);
                    unsafeAtomicAdd(&stats[128 + col], b);
                }
            }
        }
    }
}

// ---------------------------------------------------------------------------
// lin2 v7: R6's LDS-staged A + W dbuf, SWAPPED operands (vector epilogue),
// fused BN2 raw-stats (replaces the bn_stats pass; stats1-fusion-proven).
// ---------------------------------------------------------------------------
__global__ __launch_bounds__(256)
void lin2_v7_kernel(const ushort* __restrict__ Ap,   // hid [N][512] bf16
                    const ushort* __restrict__ W,    // [128][512] bf16
                    const float* __restrict__ bias,
                    const ushort* __restrict__ extb, // y1b residual
                    const float* __restrict__ rawstats,
                    const float* __restrict__ gg,
                    const float* __restrict__ bb,
                    ushort* __restrict__ outb,
                    float* __restrict__ stats2,
                    int N)
{
    constexpr int K = 512;
    __shared__ ushort alds[32 * K];      // 32 KB

    const int lane = threadIdx.x & 63, wave = threadIdx.x >> 6;
    const int lr = lane & 15, lq = lane >> 4;
    const int row0 = blockIdx.x * 32;
    const int c0w  = wave * 32;

    #pragma unroll
    for (int i = 0; i < 8; ++i) {
        int r = wave * 8 + i;
        int gr = min(row0 + r, N - 1);
        const ushort* gsrc = Ap + (size_t)gr * K + (size_t)((lane ^ (r & 7)) * 8);
        __builtin_amdgcn_global_load_lds(
            (const GLOBAL_AS void*)gsrc,
            (LDS_AS void*)(alds + (size_t)r * K),
            16, 0, 0);
    }

    bf16x8 wA[8], wB[8];
    auto loadW = [&](int kc, bf16x8 (&wd)[8]) {
        const ushort* wp0 = W + (size_t)(c0w + lr) * K + kc * 128 + lq * 8;
        #pragma unroll
        for (int t = 0; t < 4; ++t) {
            wd[t]     = *(const bf16x8*)(wp0 + t * 32);
            wd[4 + t] = *(const bf16x8*)(wp0 + (size_t)16 * K + t * 32);
        }
    };
    loadW(0, wA);
    loadW(1, wB);

    __syncthreads();

    f32x4 acc[2][2] = {};   // [s][ct]; D[i = wcol = lq*4+r][j = arow = lr]
    bf16x8 a[2][4];
    auto ldsA = [&](int kc) {
        #pragma unroll
        for (int s = 0; s < 2; ++s) {
            const ushort* lp = alds + (size_t)(s * 16 + lr) * K;
            #pragma unroll
            for (int t = 0; t < 4; ++t)
                a[s][t] = *(const bf16x8*)(lp + (kc * 16 + ((t * 4 + lq) ^ (lr & 7))) * 8);
        }
    };
    auto mf = [&](bf16x8 (&wd)[8]) {
        #pragma unroll
        for (int t = 0; t < 4; ++t) {
            acc[0][0] = __builtin_amdgcn_mfma_f32_16x16x32_bf16(wd[t],     a[0][t], acc[0][0], 0, 0, 0);
            acc[1][0] = __builtin_amdgcn_mfma_f32_16x16x32_bf16(wd[t],     a[1][t], acc[1][0], 0, 0, 0);
            acc[0][1] = __builtin_amdgcn_mfma_f32_16x16x32_bf16(wd[4 + t], a[0][t], acc[0][1], 0, 0, 0);
            acc[1][1] = __builtin_amdgcn_mfma_f32_16x16x32_bf16(wd[4 + t], a[1][t], acc[1][1], 0, 0, 0);
        }
    };

    ldsA(0); mf(wA);
    loadW(2, wA);
    ldsA(1); mf(wB);
    loadW(3, wB);
    ldsA(2); mf(wA);
    ldsA(3); mf(wB);

    float ssum[2][4] = {}, ssq[2][4] = {};

    #pragma unroll
    for (int ct = 0; ct < 2; ++ct) {
        int cb = c0w + ct * 16 + lq * 4;
        float4 rs = *(const float4*)&rawstats[cb];
        float4 rq = *(const float4*)&rawstats[128 + cb];
        float4 g4 = *(const float4*)&gg[cb];
        float4 b4 = *(const float4*)&bb[cb];
        float4 bi = *(const float4*)&bias[cb];
        float sc[4], ad[4];
        {
            float m0 = rs.x / (float)N, m1 = rs.y / (float)N,
                  m2 = rs.z / (float)N, m3 = rs.w / (float)N;
            sc[0] = g4.x * rsqrtf(rq.x / (float)N - m0 * m0 + 1e-5f);
            sc[1] = g4.y * rsqrtf(rq.y / (float)N - m1 * m1 + 1e-5f);
            sc[2] = g4.z * rsqrtf(rq.z / (float)N - m2 * m2 + 1e-5f);
            sc[3] = g4.w * rsqrtf(rq.w / (float)N - m3 * m3 + 1e-5f);
            ad[0] = bi.x + b4.x - m0 * sc[0];
            ad[1] = bi.y + b4.y - m1 * sc[1];
            ad[2] = bi.z + b4.z - m2 * sc[2];
            ad[3] = bi.w + b4.w - m3 * sc[3];
        }
        #pragma unroll
        for (int s = 0; s < 2; ++s) {
            int grow = row0 + s * 16 + lr;
            if (grow >= N) continue;
            size_t o = (size_t)grow * 128 + cb;
            ushort4 rv = *(const ushort4*)(extb + o);
            float v0 = acc[s][ct][0] + ad[0] + bf2f((short)rv.x) * sc[0];
            float v1 = acc[s][ct][1] + ad[1] + bf2f((short)rv.y) * sc[1];
            float v2 = acc[s][ct][2] + ad[2] + bf2f((short)rv.z) * sc[2];
            float v3 = acc[s][ct][3] + ad[3] + bf2f((short)rv.w) * sc[3];
            ssum[ct][0] += v0; ssq[ct][0] = fmaf(v0, v0, ssq[ct][0]);
            ssum[ct][1] += v1; ssq[ct][1] = fmaf(v1, v1, ssq[ct][1]);
            ssum[ct][2] += v2; ssq[ct][2] = fmaf(v2, v2, ssq[ct][2]);
            ssum[ct][3] += v3; ssq[ct][3] = fmaf(v3, v3, ssq[ct][3]);
            ushort4 st;
            st.x = f2bf(v0); st.y = f2bf(v1); st.z = f2bf(v2); st.w = f2bf(v3);
            *(ushort4*)(outb + o) = st;
        }
    }

    #pragma unroll
    for (int ct = 0; ct < 2; ++ct) {
        #pragma unroll
        for (int i = 0; i < 4; ++i) {
            float a = ssum[ct][i], b = ssq[ct][i];
            a += __shfl_xor(a, 1, 64);  b += __shfl_xor(b, 1, 64);
            a += __shfl_xor(a, 2, 64);  b += __shfl_xor(b, 2, 64);
            a += __shfl_xor(a, 4, 64);  b += __shfl_xor(b, 4, 64);
            a += __shfl_xor(a, 8, 64);  b += __shfl_xor(b, 8, 64);
            if (lr == 0) {
                int col = c0w + ct * 16 + lq * 4 + i;
                unsafeAtomicAdd(&stats2[col], a);
                unsafeAtomicAdd(&stats2[128 + col], b);
            }
        }
    }
}

// ---------------------------------------------------------------------------
// Merged: weight conversion + src fp32->bf16 + edge degree count.
// ---------------------------------------------------------------------------
__global__ __launch_bounds__(256)
void convert_deg_kernel(const float* __restrict__ qw, const float* __restrict__ qb,
                        const float* __restrict__ kw, const float* __restrict__ vw,
                        const float* __restrict__ ow, const float* __restrict__ w1,
                        const float* __restrict__ w2,
                        ushort* __restrict__ wqkv, ushort* __restrict__ wout,
                        ushort* __restrict__ w1b, ushort* __restrict__ w2b,
                        float* __restrict__ bqkv,
                        const float* __restrict__ src, ushort* __restrict__ srcbf,
                        int nd8,
                        const int* __restrict__ ei, long long E0,
                        int* __restrict__ deg)
{
    long long i = (long long)blockIdx.x * 256 + threadIdx.x;
    if (i < E0) atomicAdd(&deg[ei[E0 + i]], 1);
    if (i < nd8) {
        const float4* sp = (const float4*)(src + i * 8);
        float4 f0 = sp[0], f1 = sp[1];
        ushort u[8];
        u[0]=f2bf(f0.x); u[1]=f2bf(f0.y); u[2]=f2bf(f0.z); u[3]=f2bf(f0.w);
        u[4]=f2bf(f1.x); u[5]=f2bf(f1.y); u[6]=f2bf(f1.z); u[7]=f2bf(f1.w);
        *(uint4*)(srcbf + i * 8) = *(uint4*)u;
    }
    if (i < 49152) {
        int row = (int)i >> 7;
        float v;
        if (row < 128)      v = 0.25f * qw[i];
        else if (row < 256) v = kw[i - 16384];
        else                v = vw[i - 32768];
        wqkv[i] = f2bf(v);
        return;
    }
    long long j = i - 49152;
    if (j < 16384) { wout[j] = f2bf(ow[j]); return; }
    j -= 16384;
    if (j < 65536) { w1b[j] = f2bf(w1[j]); return; }
    j -= 65536;
    if (j < 65536) { w2b[j] = f2bf(w2[j]); return; }
    j -= 65536;
    if (j < 384) bqkv[j] = (j < 128) ? 0.25f * qb[j] : 0.f;
}

// ---------------------------------------------------------------------------
// Fold BN1 into lin1 weights.
// ---------------------------------------------------------------------------
__global__ __launch_bounds__(256)
void w1fold_kernel(const ushort* __restrict__ w1b, const float* __restrict__ lb1,
                   const float* __restrict__ rawstats,
                   const float* __restrict__ g1, const float* __restrict__ b1,
                   ushort* __restrict__ w1f, float* __restrict__ bias1f, int N)
{
    int f = blockIdx.x * 4 + (threadIdx.x >> 6);   // 512 rows, grid 128
    int lane = threadIdx.x & 63;
    int k0 = lane * 2;
    float m0 = rawstats[k0] / (float)N;
    float v0 = rawstats[128 + k0] / (float)N - m0 * m0;
    float sc0 = g1[k0] * rsqrtf(v0 + 1e-5f);
    float sh0 = b1[k0] - m0 * sc0;
    float m1 = rawstats[k0 + 1] / (float)N;
    float v1 = rawstats[128 + k0 + 1] / (float)N - m1 * m1;
    float sc1 = g1[k0 + 1] * rsqrtf(v1 + 1e-5f);
    float sh1 = b1[k0 + 1] - m1 * sc1;

    uint wp = *(const uint*)(w1b + (size_t)f * 128 + k0);
    float w0 = bflo(wp), w1v = bfhi(wp);
    uint o = (uint)f2bf(w0 * sc0) | ((uint)f2bf(w1v * sc1) << 16);
    *(uint*)(w1f + (size_t)f * 128 + k0) = o;

    float part = w0 * sh0 + w1v * sh1;
    #pragma unroll
    for (int m = 1; m < 64; m <<= 1) part += __shfl_xor(part, m, 64);
    if (lane == 0) bias1f[f] = lb1[f] + part;
}

// ---------------------------------------------------------------------------
// CSR build scans + scatter.
// ---------------------------------------------------------------------------
__global__ __launch_bounds__(256)
void scan_block_sum(const int* __restrict__ deg, int n, int* __restrict__ bsum)
{
    __shared__ int sh[256];
    int i = blockIdx.x * 256 + threadIdx.x;
    sh[threadIdx.x] = (i < n) ? deg[i] : 0;
    __syncthreads();
    for (int ofs = 128; ofs > 0; ofs >>= 1) {
        if (threadIdx.x < ofs) sh[threadIdx.x] += sh[threadIdx.x + ofs];
        __syncthreads();
    }
    if (threadIdx.x == 0) bsum[blockIdx.x] = sh[0];
}

__global__ __launch_bounds__(256)
void scan_final(const int* __restrict__ deg, int n, const int* __restrict__ bsum,
                int nb, int* __restrict__ rowptr)
{
    __shared__ int sb[256];
    __shared__ int sh[256];
    int t = threadIdx.x;
    sb[t] = (t < nb) ? bsum[t] : 0;
    __syncthreads();
    for (int ofs = 1; ofs < 256; ofs <<= 1) {
        int v = (t >= ofs) ? sb[t - ofs] : 0;
        __syncthreads();
        sb[t] += v;
        __syncthreads();
    }
    int boff = (blockIdx.x == 0) ? 0 : sb[blockIdx.x - 1];

    int i = blockIdx.x * 256 + t;
    int v = (i < n) ? deg[i] : 0;
    sh[t] = v;
    __syncthreads();
    for (int ofs = 1; ofs < 256; ofs <<= 1) {
        int u = (t >= ofs) ? sh[t - ofs] : 0;
        __syncthreads();
        sh[t] += u;
        __syncthreads();
    }
    if (i < n) rowptr[i] = boff + sh[t] - v;
    if (i == n - 1) rowptr[n] = boff + sh[t];
}

__global__ __launch_bounds__(256)
void scatter_kernel(const int* __restrict__ ei, long long E0,
                    const int* __restrict__ rowptr, int* __restrict__ cnt,
                    int* __restrict__ col)
{
    long long e = (long long)blockIdx.x * 256 + threadIdx.x;
    if (e >= E0) return;
    int s = ei[e], d = ei[E0 + e];
    int pos = rowptr[d] + atomicAdd(&cnt[d], 1);
    col[pos] = s;
}

// ---------------------------------------------------------------------------
// Fused gather attention, WAVE-PER-NODE, 2-deep software pipeline (R7).
// ---------------------------------------------------------------------------
__global__ __launch_bounds__(256)
void gat_agg_kernel(const int* __restrict__ rowptr, const int* __restrict__ col,
                    const ushort* __restrict__ qkv, ushort* __restrict__ agg, int N)
{
    int node = blockIdx.x * 4 + (threadIdx.x >> 6);
    if (node >= N) return;
    int lane = threadIdx.x & 63;
    int es = lane >> 3, h = lane & 7;
    const uint4* Q = (const uint4*)qkv;

    const uint4* qp = Q + (size_t)node * 48 + h * 2;
    uint4 qa = qp[0], qb = qp[1];
    float qf[16];
    qf[0]=bflo(qa.x); qf[1]=bfhi(qa.x); qf[2]=bflo(qa.y); qf[3]=bfhi(qa.y);
    qf[4]=bflo(qa.z); qf[5]=bfhi(qa.z); qf[6]=bflo(qa.w); qf[7]=bfhi(qa.w);
    qf[8]=bflo(qb.x); qf[9]=bfhi(qb.x); qf[10]=bflo(qb.y); qf[11]=bfhi(qb.y);
    qf[12]=bflo(qb.z); qf[13]=bfhi(qb.z); qf[14]=bflo(qb.w); qf[15]=bfhi(qb.w);

    float num[16];
    #pragma unroll
    for (int i = 0; i < 16; i++) num[i] = 0.f;
    float den = 0.f;

    int beg = rowptr[node];
    int total = rowptr[node + 1] - beg + 1;

    int idx = es;
    if (idx < total) {
        int s0 = (idx == 0) ? node : col[beg + idx - 1];
        const uint4* rp0 = Q + (size_t)s0 * 48 + h * 2;
        uint4 ka = rp0[16], kb = rp0[17], va = rp0[32], vb = rp0[33];
        int idx1 = idx + 8;
        int s1 = (idx1 < total) ? col[beg + idx1 - 1] : 0;

        while (true) {
            bool more = idx1 < total;
            uint4 ka1, kb1, va1, vb1;
            if (more) {
                const uint4* rp1 = Q + (size_t)s1 * 48 + h * 2;
                ka1 = rp1[16]; kb1 = rp1[17]; va1 = rp1[32]; vb1 = rp1[33];
            }
            int idx2 = idx1 + 8;
            int s2 = (idx2 < total) ? col[beg + idx2 - 1] : 0;

            float ev = __expf(dot16(qf, ka, kb));
            den += ev;
            acc16(num, ev, va, vb);

            if (!more) break;
            ka = ka1; kb = kb1; va = va1; vb = vb1;
            s1 = s2; idx1 = idx2;
        }
    }

    #pragma unroll
    for (int m = 8; m < 64; m <<= 1) {
        den += __shfl_xor(den, m, 64);
        #pragma unroll
        for (int i = 0; i < 16; i++) num[i] += __shfl_xor(num[i], m, 64);
    }

    if (es == 0) {
        float inv = 1.f / (den + 1e-16f);
        uint4 o0, o1;
        o0.x = (uint)f2bf(num[0]*inv)  | ((uint)f2bf(num[1]*inv)  << 16);
        o0.y = (uint)f2bf(num[2]*inv)  | ((uint)f2bf(num[3]*inv)  << 16);
        o0.z = (uint)f2bf(num[4]*inv)  | ((uint)f2bf(num[5]*inv)  << 16);
        o0.w = (uint)f2bf(num[6]*inv)  | ((uint)f2bf(num[7]*inv)  << 16);
        o1.x = (uint)f2bf(num[8]*inv)  | ((uint)f2bf(num[9]*inv)  << 16);
        o1.y = (uint)f2bf(num[10]*inv) | ((uint)f2bf(num[11]*inv) << 16);
        o1.z = (uint)f2bf(num[12]*inv) | ((uint)f2bf(num[13]*inv) << 16);
        o1.w = (uint)f2bf(num[14]*inv) | ((uint)f2bf(num[15]*inv) << 16);
        uint4* op = (uint4*)(agg + (size_t)node * 128 + h * 16);
        op[0] = o0; op[1] = o1;
    }
}

// final BN apply (finalize folded): bf16 in -> fp32 out
__global__ __launch_bounds__(256)
void bn_apply_out_kernel(const ushort* __restrict__ y, const float* __restrict__ rawstats,
                         const float* __restrict__ g, const float* __restrict__ b,
                         float* __restrict__ out, int total4, int N)
{
    __shared__ float scs[128], shs[128];
    if (threadIdx.x < 128) {
        int j = threadIdx.x;
        float mean = rawstats[j] / (float)N;
        float var  = rawstats[128 + j] / (float)N - mean * mean;
        float sc = g[j] * rsqrtf(var + 1e-5f);
        scs[j] = sc;
        shs[j] = b[j] - mean * sc;
    }
    __syncthreads();
    int i = blockIdx.x * 256 + threadIdx.x;
    if (i >= total4) return;
    uint2 u = reinterpret_cast<const uint2*>(y)[i];
    int j = (i * 4) & (D - 1);
    float4 v;
    v.x = bflo(u.x) * scs[j + 0] + shs[j + 0];
    v.y = bfhi(u.x) * scs[j + 1] + shs[j + 1];
    v.z = bflo(u.y) * scs[j + 2] + shs[j + 2];
    v.w = bfhi(u.y) * scs[j + 3] + shs[j + 3];
    reinterpret_cast<float4*>(out)[i] = v;
}

// ---------------------------------------------------------------------------
extern "C" void kernel_launch(void* const* d_in, const int* in_sizes, int n_in,
                              void* d_out, int out_size, void* d_ws, size_t ws_size,
                              hipStream_t stream)
{
    const float* src    = (const float*)d_in[0];
    const int*   ei     = (const int*)  d_in[1];
    const float* q_w    = (const float*)d_in[2];
    const float* q_b    = (const float*)d_in[3];
    const float* k_w    = (const float*)d_in[4];
    const float* v_w    = (const float*)d_in[5];
    const float* out_w  = (const float*)d_in[6];
    const float* out_b  = (const float*)d_in[7];
    const float* g1     = (const float*)d_in[8];
    const float* b1     = (const float*)d_in[9];
    const float* lin1_w = (const float*)d_in[10];
    const float* lin1_b = (const float*)d_in[11];
    const float* lin2_w = (const float*)d_in[12];
    const float* lin2_b = (const float*)d_in[13];
    const float* g2     = (const float*)d_in[14];
    const float* b2     = (const float*)d_in[15];

    const int N        = in_sizes[0] / D;        // 50000
    const long long E0 = in_sizes[1] / 2;        // 800000

    // ---- workspace layout (float units) ----
    float* ws = (float*)d_ws;
    size_t off = 0;
    ushort* qkv   = (ushort*)(ws + off); off += (size_t)N * 192;   // N*384 bf16
    ushort* agg   = (ushort*)(ws + off); off += (size_t)N * 64;
    ushort* srcbf = (ushort*)(ws + off); off += (size_t)N * 64;
    ushort* y1b   = (ushort*)(ws + off); off += (size_t)N * 64;
    ushort* hid   = (ushort*)(ws + off); off += (size_t)N * 256;   // N*512 bf16
    ushort* y2b   = (ushort*)(ws + off); off += (size_t)N * 64;
    ushort* wqkv  = (ushort*)(ws + off); off += 24576;             // 384*128
    ushort* woutb = (ushort*)(ws + off); off += 8192;              // 128*128
    ushort* w1b   = (ushort*)(ws + off); off += 32768;             // 512*128
    ushort* w1f   = (ushort*)(ws + off); off += 32768;             // folded
    ushort* w2b   = (ushort*)(ws + off); off += 32768;             // 128*512
    float*  bqkv  = ws + off;            off += 384;
    float*  bias1f= ws + off;            off += 512;
    size_t zero_start = off;
    int* deg    = (int*)(ws + off); off += N;
    int* cnt    = (int*)(ws + off); off += N;
    float* stats1 = ws + off; off += 512;
    float* stats2 = ws + off; off += 512;
    size_t zero_cnt = off - zero_start;
    int* rowptr = (int*)(ws + off); off += N + 1;
    int* bsum   = (int*)(ws + off); off += 256;
    int* col    = (int*)(ws + off); off += E0;

    hipMemsetAsync(ws + zero_start, 0, zero_cnt * sizeof(float), stream);

    dim3 blk(256);

    // ---- merged weight conversion + src->bf16 + degree count ----
    dim3 gE0((unsigned)((E0 + 255) / 256));
    hipLaunchKernelGGL(convert_deg_kernel, gE0, blk, 0, stream,
                       q_w, q_b, k_w, v_w, out_w, lin1_w, lin2_w,
                       wqkv, woutb, w1b, w2b, bqkv,
                       src, srcbf, N * 16, ei, E0, deg);

    // ---- CSR scans + scatter ----
    int nb = (N + 255) / 256;
    hipLaunchKernelGGL(scan_block_sum, dim3(nb), blk, 0, stream, deg, N, bsum);
    hipLaunchKernelGGL(scan_final, dim3(nb), blk, 0, stream, deg, N, bsum, nb, rowptr);
    hipLaunchKernelGGL(scatter_kernel, gE0, blk, 0, stream, ei, E0, rowptr, cnt, col);

    const int gx = 1024;   // grid-stride row blocks

    // ---- QKV projection (LDS-staged A, vector epilogue), M=384 ----
    hipLaunchKernelGGL((gemm_v8_kernel<0, 384, 0>), dim3(gx, 3), blk, 0, stream,
                       srcbf, wqkv, bqkv, nullptr, qkv, nullptr, N);

    // ---- fused softmax + aggregation (wave per node, pipelined) ----
    hipLaunchKernelGGL(gat_agg_kernel, dim3((N + 3) / 4), blk, 0, stream,
                       rowptr, col, qkv, agg, N);

    // ---- out-projection + bias + fp32 src residual -> y1b, fused BN1 stats ----
    hipLaunchKernelGGL((gemm_v8_kernel<3, 128, 1>), dim3(gx, 1), blk, 0, stream,
                       agg, woutb, out_b, src, y1b, stats1, N);

    // ---- fold BN1 into lin1 weights ----
    hipLaunchKernelGGL(w1fold_kernel, dim3(128), blk, 0, stream,
                       w1b, lin1_b, stats1, g1, b1, w1f, bias1f, N);

    // ---- lin1 (LDS-staged A, folded BN) + leaky -> hid, M=512 ----
    hipLaunchKernelGGL((gemm_v8_kernel<2, 512, 0>), dim3(gx, 4), blk, 0, stream,
                       y1b, w1f, bias1f, nullptr, hid, nullptr, N);

    // ---- lin2 v7: LDS-staged A + W dbuf + BN1 residual + fused BN2 stats ----
    hipLaunchKernelGGL(lin2_v7_kernel, dim3((N + 31) / 32), blk, 0, stream,
                       hid, w2b, lin2_b, y1b, stats1, g1, b1, y2b, stats2, N);

    // ---- BN2 apply -> d_out fp32 ----
    int total4 = N * D / 4;
    hipLaunchKernelGGL(bn_apply_out_kernel, dim3((total4 + 255) / 256), blk, 0, stream,
                       y2b, stats2, g2, b2, (float*)d_out, total4, N);
}

// Round 10
// 389.928 us; speedup vs baseline: 1.4997x; 1.4997x over previous
//
#include <hip/hip_runtime.h>
#include <math.h>

#define D 128
#define H 8
#define HD 16

typedef __attribute__((ext_vector_type(8))) short bf16x8;
typedef __attribute__((ext_vector_type(4))) float f32x4;

#define GLOBAL_AS __attribute__((address_space(1)))
#define LDS_AS    __attribute__((address_space(3)))

__device__ __forceinline__ ushort f2bf(float x) {
    union { float f; unsigned u; } v; v.f = x;
    unsigned r = v.u + 0x7fffu + ((v.u >> 16) & 1u);   // RNE
    return (ushort)(r >> 16);
}
__device__ __forceinline__ float bflo(unsigned u) {
    union { unsigned u; float f; } x; x.u = u << 16; return x.f;
}
__device__ __forceinline__ float bfhi(unsigned u) {
    union { unsigned u; float f; } x; x.u = u & 0xffff0000u; return x.f;
}
__device__ __forceinline__ float bf2f(short s) {
    union { unsigned u; float f; } x; x.u = ((unsigned)(ushort)s) << 16; return x.f;
}

__device__ __forceinline__ float dot16(const float* qf, uint4 a, uint4 b) {
    float w;
    w  = qf[0]  * bflo(a.x) + qf[1]  * bfhi(a.x);
    w += qf[2]  * bflo(a.y) + qf[3]  * bfhi(a.y);
    w += qf[4]  * bflo(a.z) + qf[5]  * bfhi(a.z);
    w += qf[6]  * bflo(a.w) + qf[7]  * bfhi(a.w);
    w += qf[8]  * bflo(b.x) + qf[9]  * bfhi(b.x);
    w += qf[10] * bflo(b.y) + qf[11] * bfhi(b.y);
    w += qf[12] * bflo(b.z) + qf[13] * bfhi(b.z);
    w += qf[14] * bflo(b.w) + qf[15] * bfhi(b.w);
    return w;
}
__device__ __forceinline__ void acc16(float* num, float e, uint4 a, uint4 b) {
    num[0]  = fmaf(e, bflo(a.x), num[0]);  num[1]  = fmaf(e, bfhi(a.x), num[1]);
    num[2]  = fmaf(e, bflo(a.y), num[2]);  num[3]  = fmaf(e, bfhi(a.y), num[3]);
    num[4]  = fmaf(e, bflo(a.z), num[4]);  num[5]  = fmaf(e, bfhi(a.z), num[5]);
    num[6]  = fmaf(e, bflo(a.w), num[6]);  num[7]  = fmaf(e, bfhi(a.w), num[7]);
    num[8]  = fmaf(e, bflo(b.x), num[8]);  num[9]  = fmaf(e, bfhi(b.x), num[9]);
    num[10] = fmaf(e, bflo(b.y), num[10]); num[11] = fmaf(e, bfhi(b.y), num[11]);
    num[12] = fmaf(e, bflo(b.z), num[12]); num[13] = fmaf(e, bfhi(b.z), num[13]);
    num[14] = fmaf(e, bflo(b.w), num[14]); num[15] = fmaf(e, bfhi(b.w), num[15]);
}

// ---------------------------------------------------------------------------
// GEMM v7: v4's B-stationary skeleton + R6-proven LDS A-staging.
// (R8-proven configuration; R9's operand-swap variant regressed — reverted.)
// ---------------------------------------------------------------------------
template<int EPI, int M, int STATS>
__global__ __launch_bounds__(256)
void gemm_v7_kernel(const ushort* __restrict__ A,
                    const ushort* __restrict__ W,
                    const float* __restrict__ bias,
                    const float* __restrict__ extf,
                    ushort* __restrict__ outb,
                    float* __restrict__ stats,
                    int N)
{
    __shared__ ushort alds[2][32 * 128];   // 2 x 8KB

    const int lane = threadIdx.x & 63, wave = threadIdx.x >> 6;
    const int lr = lane & 15, lq = lane >> 4;
    const int colbase = blockIdx.y * 128 + wave * 32;

    // resident B: 2 col-groups x 4 k-tiles (v4-proven)
    bf16x8 bfr[2][4];
    {
        const ushort* wp = W + (size_t)(colbase + lr) * 128 + lq * 8;
        #pragma unroll
        for (int ct = 0; ct < 2; ++ct)
            #pragma unroll
            for (int t = 0; t < 4; ++t)
                bfr[ct][t] = *(const bf16x8*)(wp + (size_t)ct * 16 * 128 + t * 32);
    }
    float biasv[2];
    biasv[0] = bias[colbase + lr];
    biasv[1] = bias[colbase + 16 + lr];

    float ssum[2] = {0.f, 0.f}, ssq[2] = {0.f, 0.f};

    // stage one 32x128 tile into buffer b: wave w covers rows w*8..w*8+7,
    // 2 gld_lds of 1KB (4 rows) each. LDS dest = uniform base + lane*16
    // -> row w*8+i*4+(lane>>4), chunk lane&15. Global src chunk ^(r&7).
    auto stage = [&](int rb, int b) {
        #pragma unroll
        for (int i = 0; i < 2; ++i) {
            int r = wave * 8 + i * 4 + (lane >> 4);
            int gr = min(rb + r, N - 1);
            int c = (lane & 15) ^ (r & 7);
            __builtin_amdgcn_global_load_lds(
                (const GLOBAL_AS void*)(A + (size_t)gr * 128 + c * 8),
                (LDS_AS void*)(&alds[b][(wave * 8 + i * 4) * 128]),
                16, 0, 0);
        }
    };

    const int stride = gridDim.x * 32;
    int r0 = blockIdx.x * 32;

    stage(r0, 0);
    __syncthreads();
    int cur = 0;

    while (true) {
        int rn = r0 + stride;
        if (rn < N) stage(rn, cur ^ 1);    // async, overlaps compute below

        // A fragments from LDS (swizzled read)
        bf16x8 a[2][4];
        #pragma unroll
        for (int s = 0; s < 2; ++s) {
            const ushort* lp = &alds[cur][(s * 16 + lr) * 128];
            #pragma unroll
            for (int t = 0; t < 4; ++t)
                a[s][t] = *(const bf16x8*)(lp + ((t * 4 + lq) ^ (lr & 7)) * 8);
        }

        f32x4 acc[2][2] = {};
        #pragma unroll
        for (int t = 0; t < 4; ++t) {
            acc[0][0] = __builtin_amdgcn_mfma_f32_16x16x32_bf16(a[0][t], bfr[0][t], acc[0][0], 0, 0, 0);
            acc[1][0] = __builtin_amdgcn_mfma_f32_16x16x32_bf16(a[1][t], bfr[0][t], acc[1][0], 0, 0, 0);
            acc[0][1] = __builtin_amdgcn_mfma_f32_16x16x32_bf16(a[0][t], bfr[1][t], acc[0][1], 0, 0, 0);
            acc[1][1] = __builtin_amdgcn_mfma_f32_16x16x32_bf16(a[1][t], bfr[1][t], acc[1][1], 0, 0, 0);
        }

        #pragma unroll
        for (int ct = 0; ct < 2; ++ct) {
            int gcol = colbase + ct * 16 + lr;
            #pragma unroll
            for (int s = 0; s < 2; ++s) {
                #pragma unroll
                for (int r = 0; r < 4; ++r) {
                    int grow = r0 + s * 16 + lq * 4 + r;
                    if (grow >= N) continue;
                    size_t o = (size_t)grow * M + gcol;
                    float v = acc[s][ct][r] + biasv[ct];
                    if (EPI == 2)      v = v > 0.f ? v : 0.01f * v;
                    else if (EPI == 3) v += extf[o];
                    if (STATS) { ssum[ct] += v; ssq[ct] = fmaf(v, v, ssq[ct]); }
                    outb[o] = f2bf(v);
                }
            }
        }

        if (rn >= N) break;
        __syncthreads();   // drains stage(rn) + all waves done reading alds[cur]
        cur ^= 1;
        r0 = rn;
    }

    if (STATS) {
        #pragma unroll
        for (int ct = 0; ct < 2; ++ct) {
            float a = ssum[ct], b = ssq[ct];
            a += __shfl_xor(a, 16, 64);  b += __shfl_xor(b, 16, 64);
            a += __shfl_xor(a, 32, 64);  b += __shfl_xor(b, 32, 64);
            if (lq == 0) {
                unsafeAtomicAdd(&stats[colbase + ct * 16 + lr], a);
                unsafeAtomicAdd(&stats[128 + colbase + ct * 16 + lr], b);
            }
        }
    }
}

// ---------------------------------------------------------------------------
// lin2 v6: LDS-staged A (global_load_lds) + W dbuf (R6-proven, unchanged).
// ---------------------------------------------------------------------------
__global__ __launch_bounds__(256)
void lin2_v6_kernel(const ushort* __restrict__ Ap,   // hid [N][512] bf16
                    const ushort* __restrict__ W,    // [128][512] bf16
                    const float* __restrict__ bias,
                    const ushort* __restrict__ extb, // y1b residual
                    const float* __restrict__ rawstats,
                    const float* __restrict__ gg,
                    const float* __restrict__ bb,
                    ushort* __restrict__ outb,
                    int N)
{
    constexpr int K = 512;
    __shared__ ushort alds[32 * K];      // 32 KB

    const int lane = threadIdx.x & 63, wave = threadIdx.x >> 6;
    const int lr = lane & 15, lq = lane >> 4;
    const int row0 = blockIdx.x * 32;
    const int c0w  = wave * 32;

    #pragma unroll
    for (int i = 0; i < 8; ++i) {
        int r = wave * 8 + i;
        int gr = min(row0 + r, N - 1);
        const ushort* gsrc = Ap + (size_t)gr * K + (size_t)((lane ^ (r & 7)) * 8);
        __builtin_amdgcn_global_load_lds(
            (const GLOBAL_AS void*)gsrc,
            (LDS_AS void*)(alds + (size_t)r * K),
            16, 0, 0);
    }

    bf16x8 wA[8], wB[8];
    auto loadW = [&](int kc, bf16x8 (&wd)[8]) {
        const ushort* wp0 = W + (size_t)(c0w + lr) * K + kc * 128 + lq * 8;
        #pragma unroll
        for (int t = 0; t < 4; ++t) {
            wd[t]     = *(const bf16x8*)(wp0 + t * 32);
            wd[4 + t] = *(const bf16x8*)(wp0 + (size_t)16 * K + t * 32);
        }
    };
    loadW(0, wA);
    loadW(1, wB);

    __syncthreads();

    f32x4 acc[2][2] = {};
    bf16x8 a[2][4];
    auto ldsA = [&](int kc) {
        #pragma unroll
        for (int s = 0; s < 2; ++s) {
            const ushort* lp = alds + (size_t)(s * 16 + lr) * K;
            #pragma unroll
            for (int t = 0; t < 4; ++t)
                a[s][t] = *(const bf16x8*)(lp + (kc * 16 + ((t * 4 + lq) ^ (lr & 7))) * 8);
        }
    };
    auto mf = [&](bf16x8 (&wd)[8]) {
        #pragma unroll
        for (int t = 0; t < 4; ++t) {
            acc[0][0] = __builtin_amdgcn_mfma_f32_16x16x32_bf16(a[0][t], wd[t],     acc[0][0], 0, 0, 0);
            acc[1][0] = __builtin_amdgcn_mfma_f32_16x16x32_bf16(a[1][t], wd[t],     acc[1][0], 0, 0, 0);
            acc[0][1] = __builtin_amdgcn_mfma_f32_16x16x32_bf16(a[0][t], wd[4 + t], acc[0][1], 0, 0, 0);
            acc[1][1] = __builtin_amdgcn_mfma_f32_16x16x32_bf16(a[1][t], wd[4 + t], acc[1][1], 0, 0, 0);
        }
    };

    ldsA(0); mf(wA);
    loadW(2, wA);
    ldsA(1); mf(wB);
    loadW(3, wB);
    ldsA(2); mf(wA);
    ldsA(3); mf(wB);

    #pragma unroll
    for (int ct = 0; ct < 2; ++ct) {
        int col = c0w + ct * 16 + lr;
        float biasv = bias[col];
        float mean = rawstats[col] / (float)N;
        float var  = rawstats[128 + col] / (float)N - mean * mean;
        float scv = gg[col] * rsqrtf(var + 1e-5f);
        float shv = bb[col] - mean * scv;
        #pragma unroll
        for (int s = 0; s < 2; ++s) {
            #pragma unroll
            for (int r = 0; r < 4; ++r) {
                int grow = row0 + s * 16 + lq * 4 + r;
                if (grow >= N) continue;
                size_t o = (size_t)grow * 128 + col;
                float v = acc[s][ct][r] + biasv + fmaf(bf2f((short)extb[o]), scv, shv);
                outb[o] = f2bf(v);
            }
        }
    }
}

// ---------------------------------------------------------------------------
// Merged: weight conversion + src fp32->bf16 + edge degree count.
// ---------------------------------------------------------------------------
__global__ __launch_bounds__(256)
void convert_deg_kernel(const float* __restrict__ qw, const float* __restrict__ qb,
                        const float* __restrict__ kw, const float* __restrict__ vw,
                        const float* __restrict__ ow, const float* __restrict__ w1,
                        const float* __restrict__ w2,
                        ushort* __restrict__ wqkv, ushort* __restrict__ wout,
                        ushort* __restrict__ w1b, ushort* __restrict__ w2b,
                        float* __restrict__ bqkv,
                        const float* __restrict__ src, ushort* __restrict__ srcbf,
                        int nd8,
                        const int* __restrict__ ei, long long E0,
                        int* __restrict__ deg)
{
    long long i = (long long)blockIdx.x * 256 + threadIdx.x;
    if (i < E0) atomicAdd(&deg[ei[E0 + i]], 1);
    if (i < nd8) {
        const float4* sp = (const float4*)(src + i * 8);
        float4 f0 = sp[0], f1 = sp[1];
        ushort u[8];
        u[0]=f2bf(f0.x); u[1]=f2bf(f0.y); u[2]=f2bf(f0.z); u[3]=f2bf(f0.w);
        u[4]=f2bf(f1.x); u[5]=f2bf(f1.y); u[6]=f2bf(f1.z); u[7]=f2bf(f1.w);
        *(uint4*)(srcbf + i * 8) = *(uint4*)u;
    }
    if (i < 49152) {
        int row = (int)i >> 7;
        float v;
        if (row < 128)      v = 0.25f * qw[i];
        else if (row < 256) v = kw[i - 16384];
        else                v = vw[i - 32768];
        wqkv[i] = f2bf(v);
        return;
    }
    long long j = i - 49152;
    if (j < 16384) { wout[j] = f2bf(ow[j]); return; }
    j -= 16384;
    if (j < 65536) { w1b[j] = f2bf(w1[j]); return; }
    j -= 65536;
    if (j < 65536) { w2b[j] = f2bf(w2[j]); return; }
    j -= 65536;
    if (j < 384) bqkv[j] = (j < 128) ? 0.25f * qb[j] : 0.f;
}

// ---------------------------------------------------------------------------
// Fold BN1 into lin1 weights.
// ---------------------------------------------------------------------------
__global__ __launch_bounds__(256)
void w1fold_kernel(const ushort* __restrict__ w1b, const float* __restrict__ lb1,
                   const float* __restrict__ rawstats,
                   const float* __restrict__ g1, const float* __restrict__ b1,
                   ushort* __restrict__ w1f, float* __restrict__ bias1f, int N)
{
    int f = blockIdx.x * 4 + (threadIdx.x >> 6);   // 512 rows, grid 128
    int lane = threadIdx.x & 63;
    int k0 = lane * 2;
    float m0 = rawstats[k0] / (float)N;
    float v0 = rawstats[128 + k0] / (float)N - m0 * m0;
    float sc0 = g1[k0] * rsqrtf(v0 + 1e-5f);
    float sh0 = b1[k0] - m0 * sc0;
    float m1 = rawstats[k0 + 1] / (float)N;
    float v1 = rawstats[128 + k0 + 1] / (float)N - m1 * m1;
    float sc1 = g1[k0 + 1] * rsqrtf(v1 + 1e-5f);
    float sh1 = b1[k0 + 1] - m1 * sc1;

    uint wp = *(const uint*)(w1b + (size_t)f * 128 + k0);
    float w0 = bflo(wp), w1v = bfhi(wp);
    uint o = (uint)f2bf(w0 * sc0) | ((uint)f2bf(w1v * sc1) << 16);
    *(uint*)(w1f + (size_t)f * 128 + k0) = o;

    float part = w0 * sh0 + w1v * sh1;
    #pragma unroll
    for (int m = 1; m < 64; m <<= 1) part += __shfl_xor(part, m, 64);
    if (lane == 0) bias1f[f] = lb1[f] + part;
}

// ---------------------------------------------------------------------------
// CSR build scans + scatter.
// ---------------------------------------------------------------------------
__global__ __launch_bounds__(256)
void scan_block_sum(const int* __restrict__ deg, int n, int* __restrict__ bsum)
{
    __shared__ int sh[256];
    int i = blockIdx.x * 256 + threadIdx.x;
    sh[threadIdx.x] = (i < n) ? deg[i] : 0;
    __syncthreads();
    for (int ofs = 128; ofs > 0; ofs >>= 1) {
        if (threadIdx.x < ofs) sh[threadIdx.x] += sh[threadIdx.x + ofs];
        __syncthreads();
    }
    if (threadIdx.x == 0) bsum[blockIdx.x] = sh[0];
}

__global__ __launch_bounds__(256)
void scan_final(const int* __restrict__ deg, int n, const int* __restrict__ bsum,
                int nb, int* __restrict__ rowptr)
{
    __shared__ int sb[256];
    __shared__ int sh[256];
    int t = threadIdx.x;
    sb[t] = (t < nb) ? bsum[t] : 0;
    __syncthreads();
    for (int ofs = 1; ofs < 256; ofs <<= 1) {
        int v = (t >= ofs) ? sb[t - ofs] : 0;
        __syncthreads();
        sb[t] += v;
        __syncthreads();
    }
    int boff = (blockIdx.x == 0) ? 0 : sb[blockIdx.x - 1];

    int i = blockIdx.x * 256 + t;
    int v = (i < n) ? deg[i] : 0;
    sh[t] = v;
    __syncthreads();
    for (int ofs = 1; ofs < 256; ofs <<= 1) {
        int u = (t >= ofs) ? sh[t - ofs] : 0;
        __syncthreads();
        sh[t] += u;
        __syncthreads();
    }
    if (i < n) rowptr[i] = boff + sh[t] - v;
    if (i == n - 1) rowptr[n] = boff + sh[t];
}

__global__ __launch_bounds__(256)
void scatter_kernel(const int* __restrict__ ei, long long E0,
                    const int* __restrict__ rowptr, int* __restrict__ cnt,
                    int* __restrict__ col)
{
    long long e = (long long)blockIdx.x * 256 + threadIdx.x;
    if (e >= E0) return;
    int s = ei[e], d = ei[E0 + e];
    int pos = rowptr[d] + atomicAdd(&cnt[d], 1);
    col[pos] = s;
}

// ---------------------------------------------------------------------------
// Fused gather attention, WAVE-PER-NODE, 2-deep software pipeline (R7).
// ---------------------------------------------------------------------------
__global__ __launch_bounds__(256)
void gat_agg_kernel(const int* __restrict__ rowptr, const int* __restrict__ col,
                    const ushort* __restrict__ qkv, ushort* __restrict__ agg, int N)
{
    int node = blockIdx.x * 4 + (threadIdx.x >> 6);
    if (node >= N) return;
    int lane = threadIdx.x & 63;
    int es = lane >> 3, h = lane & 7;
    const uint4* Q = (const uint4*)qkv;

    const uint4* qp = Q + (size_t)node * 48 + h * 2;
    uint4 qa = qp[0], qb = qp[1];
    float qf[16];
    qf[0]=bflo(qa.x); qf[1]=bfhi(qa.x); qf[2]=bflo(qa.y); qf[3]=bfhi(qa.y);
    qf[4]=bflo(qa.z); qf[5]=bfhi(qa.z); qf[6]=bflo(qa.w); qf[7]=bfhi(qa.w);
    qf[8]=bflo(qb.x); qf[9]=bfhi(qb.x); qf[10]=bflo(qb.y); qf[11]=bfhi(qb.y);
    qf[12]=bflo(qb.z); qf[13]=bfhi(qb.z); qf[14]=bflo(qb.w); qf[15]=bfhi(qb.w);

    float num[16];
    #pragma unroll
    for (int i = 0; i < 16; i++) num[i] = 0.f;
    float den = 0.f;

    int beg = rowptr[node];
    int total = rowptr[node + 1] - beg + 1;

    int idx = es;
    if (idx < total) {
        int s0 = (idx == 0) ? node : col[beg + idx - 1];
        const uint4* rp0 = Q + (size_t)s0 * 48 + h * 2;
        uint4 ka = rp0[16], kb = rp0[17], va = rp0[32], vb = rp0[33];
        int idx1 = idx + 8;
        int s1 = (idx1 < total) ? col[beg + idx1 - 1] : 0;

        while (true) {
            bool more = idx1 < total;
            uint4 ka1, kb1, va1, vb1;
            if (more) {
                const uint4* rp1 = Q + (size_t)s1 * 48 + h * 2;
                ka1 = rp1[16]; kb1 = rp1[17]; va1 = rp1[32]; vb1 = rp1[33];
            }
            int idx2 = idx1 + 8;
            int s2 = (idx2 < total) ? col[beg + idx2 - 1] : 0;

            float ev = __expf(dot16(qf, ka, kb));
            den += ev;
            acc16(num, ev, va, vb);

            if (!more) break;
            ka = ka1; kb = kb1; va = va1; vb = vb1;
            s1 = s2; idx1 = idx2;
        }
    }

    #pragma unroll
    for (int m = 8; m < 64; m <<= 1) {
        den += __shfl_xor(den, m, 64);
        #pragma unroll
        for (int i = 0; i < 16; i++) num[i] += __shfl_xor(num[i], m, 64);
    }

    if (es == 0) {
        float inv = 1.f / (den + 1e-16f);
        uint4 o0, o1;
        o0.x = (uint)f2bf(num[0]*inv)  | ((uint)f2bf(num[1]*inv)  << 16);
        o0.y = (uint)f2bf(num[2]*inv)  | ((uint)f2bf(num[3]*inv)  << 16);
        o0.z = (uint)f2bf(num[4]*inv)  | ((uint)f2bf(num[5]*inv)  << 16);
        o0.w = (uint)f2bf(num[6]*inv)  | ((uint)f2bf(num[7]*inv)  << 16);
        o1.x = (uint)f2bf(num[8]*inv)  | ((uint)f2bf(num[9]*inv)  << 16);
        o1.y = (uint)f2bf(num[10]*inv) | ((uint)f2bf(num[11]*inv) << 16);
        o1.z = (uint)f2bf(num[12]*inv) | ((uint)f2bf(num[13]*inv) << 16);
        o1.w = (uint)f2bf(num[14]*inv) | ((uint)f2bf(num[15]*inv) << 16);
        uint4* op = (uint4*)(agg + (size_t)node * 128 + h * 16);
        op[0] = o0; op[1] = o1;
    }
}

// ---------------------------------------------------------------------------
// BatchNorm raw stats over bf16 [N x 128]  (R0-proven, ~7us).
// ---------------------------------------------------------------------------
__global__ __launch_bounds__(256)
void bn_stats_bf16_kernel(const ushort* __restrict__ y, int N, float* __restrict__ stats)
{
    int jp = threadIdx.x & 63;
    int q4 = threadIdx.x >> 6;
    int r = blockIdx.x * 256 + q4;
    int rend = min(N, (int)(blockIdx.x + 1) * 256);
    float s0 = 0.f, qq0 = 0.f, s1 = 0.f, qq1 = 0.f;
    const uint* yp = (const uint*)y;
    for (; r < rend; r += 4) {
        uint u = yp[(size_t)r * 64 + jp];
        float a = bflo(u), b = bfhi(u);
        s0 += a; qq0 += a * a; s1 += b; qq1 += b * b;
    }
    __shared__ float sh[4][64][4];
    sh[q4][jp][0] = s0; sh[q4][jp][1] = qq0; sh[q4][jp][2] = s1; sh[q4][jp][3] = qq1;
    __syncthreads();
    if (threadIdx.x < 128) {
        int p = threadIdx.x >> 1;
        int w = threadIdx.x & 1;
        float ss = 0.f, sq = 0.f;
        #pragma unroll
        for (int i = 0; i < 4; i++) { ss += sh[i][p][w * 2]; sq += sh[i][p][w * 2 + 1]; }
        unsafeAtomicAdd(&stats[2 * p + w], ss);
        unsafeAtomicAdd(&stats[128 + 2 * p + w], sq);
    }
}

// final BN apply (finalize folded): bf16 in -> fp32 out
__global__ __launch_bounds__(256)
void bn_apply_out_kernel(const ushort* __restrict__ y, const float* __restrict__ rawstats,
                         const float* __restrict__ g, const float* __restrict__ b,
                         float* __restrict__ out, int total4, int N)
{
    __shared__ float scs[128], shs[128];
    if (threadIdx.x < 128) {
        int j = threadIdx.x;
        float mean = rawstats[j] / (float)N;
        float var  = rawstats[128 + j] / (float)N - mean * mean;
        float sc = g[j] * rsqrtf(var + 1e-5f);
        scs[j] = sc;
        shs[j] = b[j] - mean * sc;
    }
    __syncthreads();
    int i = blockIdx.x * 256 + threadIdx.x;
    if (i >= total4) return;
    uint2 u = reinterpret_cast<const uint2*>(y)[i];
    int j = (i * 4) & (D - 1);
    float4 v;
    v.x = bflo(u.x) * scs[j + 0] + shs[j + 0];
    v.y = bfhi(u.x) * scs[j + 1] + shs[j + 1];
    v.z = bflo(u.y) * scs[j + 2] + shs[j + 2];
    v.w = bfhi(u.y) * scs[j + 3] + shs[j + 3];
    reinterpret_cast<float4*>(out)[i] = v;
}

// ---------------------------------------------------------------------------
extern "C" void kernel_launch(void* const* d_in, const int* in_sizes, int n_in,
                              void* d_out, int out_size, void* d_ws, size_t ws_size,
                              hipStream_t stream)
{
    const float* src    = (const float*)d_in[0];
    const int*   ei     = (const int*)  d_in[1];
    const float* q_w    = (const float*)d_in[2];
    const float* q_b    = (const float*)d_in[3];
    const float* k_w    = (const float*)d_in[4];
    const float* v_w    = (const float*)d_in[5];
    const float* out_w  = (const float*)d_in[6];
    const float* out_b  = (const float*)d_in[7];
    const float* g1     = (const float*)d_in[8];
    const float* b1     = (const float*)d_in[9];
    const float* lin1_w = (const float*)d_in[10];
    const float* lin1_b = (const float*)d_in[11];
    const float* lin2_w = (const float*)d_in[12];
    const float* lin2_b = (const float*)d_in[13];
    const float* g2     = (const float*)d_in[14];
    const float* b2     = (const float*)d_in[15];

    const int N        = in_sizes[0] / D;        // 50000
    const long long E0 = in_sizes[1] / 2;        // 800000

    // ---- workspace layout (float units) ----
    float* ws = (float*)d_ws;
    size_t off = 0;
    ushort* qkv   = (ushort*)(ws + off); off += (size_t)N * 192;   // N*384 bf16
    ushort* agg   = (ushort*)(ws + off); off += (size_t)N * 64;
    ushort* srcbf = (ushort*)(ws + off); off += (size_t)N * 64;
    ushort* y1b   = (ushort*)(ws + off); off += (size_t)N * 64;
    ushort* hid   = (ushort*)(ws + off); off += (size_t)N * 256;   // N*512 bf16
    ushort* y2b   = (ushort*)(ws + off); off += (size_t)N * 64;
    ushort* wqkv  = (ushort*)(ws + off); off += 24576;             // 384*128
    ushort* woutb = (ushort*)(ws + off); off += 8192;              // 128*128
    ushort* w1b   = (ushort*)(ws + off); off += 32768;             // 512*128
    ushort* w1f   = (ushort*)(ws + off); off += 32768;             // folded
    ushort* w2b   = (ushort*)(ws + off); off += 32768;             // 128*512
    float*  bqkv  = ws + off;            off += 384;
    float*  bias1f= ws + off;            off += 512;
    size_t zero_start = off;
    int* deg    = (int*)(ws + off); off += N;
    int* cnt    = (int*)(ws + off); off += N;
    float* stats1 = ws + off; off += 512;
    float* stats2 = ws + off; off += 512;
    size_t zero_cnt = off - zero_start;
    int* rowptr = (int*)(ws + off); off += N + 1;
    int* bsum   = (int*)(ws + off); off += 256;
    int* col    = (int*)(ws + off); off += E0;

    hipMemsetAsync(ws + zero_start, 0, zero_cnt * sizeof(float), stream);

    dim3 blk(256);

    // ---- merged weight conversion + src->bf16 + degree count ----
    dim3 gE0((unsigned)((E0 + 255) / 256));
    hipLaunchKernelGGL(convert_deg_kernel, gE0, blk, 0, stream,
                       q_w, q_b, k_w, v_w, out_w, lin1_w, lin2_w,
                       wqkv, woutb, w1b, w2b, bqkv,
                       src, srcbf, N * 16, ei, E0, deg);

    // ---- CSR scans + scatter ----
    int nb = (N + 255) / 256;
    hipLaunchKernelGGL(scan_block_sum, dim3(nb), blk, 0, stream, deg, N, bsum);
    hipLaunchKernelGGL(scan_final, dim3(nb), blk, 0, stream, deg, N, bsum, nb, rowptr);
    hipLaunchKernelGGL(scatter_kernel, gE0, blk, 0, stream, ei, E0, rowptr, cnt, col);

    const int gx = 1024;   // grid-stride row blocks

    // ---- QKV projection (LDS-staged A), M=384 ----
    hipLaunchKernelGGL((gemm_v7_kernel<0, 384, 0>), dim3(gx, 3), blk, 0, stream,
                       srcbf, wqkv, bqkv, nullptr, qkv, nullptr, N);

    // ---- fused softmax + aggregation (wave per node, pipelined) ----
    hipLaunchKernelGGL(gat_agg_kernel, dim3((N + 3) / 4), blk, 0, stream,
                       rowptr, col, qkv, agg, N);

    // ---- out-projection + bias + fp32 src residual -> y1b, fused BN1 stats ----
    hipLaunchKernelGGL((gemm_v7_kernel<3, 128, 1>), dim3(gx, 1), blk, 0, stream,
                       agg, woutb, out_b, src, y1b, stats1, N);

    // ---- fold BN1 into lin1 weights ----
    hipLaunchKernelGGL(w1fold_kernel, dim3(128), blk, 0, stream,
                       w1b, lin1_b, stats1, g1, b1, w1f, bias1f, N);

    // ---- lin1 (LDS-staged A, folded BN) + leaky -> hid, M=512 ----
    hipLaunchKernelGGL((gemm_v7_kernel<2, 512, 0>), dim3(gx, 4), blk, 0, stream,
                       y1b, w1f, bias1f, nullptr, hid, nullptr, N);

    // ---- lin2 v6: LDS-staged A + W dbuf + bias + BN1 residual -> y2b ----
    hipLaunchKernelGGL(lin2_v6_kernel, dim3((N + 31) / 32), blk, 0, stream,
                       hid, w2b, lin2_b, y1b, stats1, g1, b1, y2b, N);

    // ---- BN2 stats + apply -> d_out fp32 ----
    dim3 gS((N + 255) / 256);
    hipLaunchKernelGGL(bn_stats_bf16_kernel, gS, blk, 0, stream, y2b, N, stats2);
    int total4 = N * D / 4;
    hipLaunchKernelGGL(bn_apply_out_kernel, dim3((total4 + 255) / 256), blk, 0, stream,
                       y2b, stats2, g2, b2, (float*)d_out, total4, N);
}